// Round 2
// baseline (407.243 us; speedup 1.0000x reference)
//
#include <hip/hip_runtime.h>
#include <stdint.h>

#define NN 10000
#define NE 100000

__device__ __forceinline__ float bu2f(uint16_t u) {
    return __uint_as_float(((uint32_t)u) << 16);
}
__device__ __forceinline__ float blo(uint32_t v) { return __uint_as_float(v << 16); }
__device__ __forceinline__ float bhi(uint32_t v) { return __uint_as_float(v & 0xffff0000u); }
__device__ __forceinline__ uint16_t f2bu(float f) {  // RNE
    uint32_t u = __float_as_uint(f);
    return (uint16_t)((u + 0x7fffu + ((u >> 16) & 1u)) >> 16);
}
__device__ __forceinline__ float ldf(const void* p, size_t i, int f32) {
    return f32 ? ((const float*)p)[i] : bu2f(((const uint16_t*)p)[i]);
}
__device__ __forceinline__ void stf(void* p, size_t i, float v, int f32) {
    if (f32) ((float*)p)[i] = v;
    else ((uint16_t*)p)[i] = f2bu(v);
}

__global__ void k_detect(const void* __restrict__ x, int* __restrict__ flag) {
    if (threadIdx.x == 0 && blockIdx.x == 0) {
        const uint16_t* p = (const uint16_t*)x;
        int c = 0;
        for (int i = 0; i < 1024; i++) {
            float a = fabsf(bu2f(p[i]));
            if (a > 1e-3f && a < 16.0f) c++;
        }
        *flag = (c < 870) ? 1 : 0;  // 1 = fp32 inputs
    }
}

__global__ __launch_bounds__(256) void k_edge_mlp(
    const void* __restrict__ edge_attr, const void* __restrict__ w1,
    const void* __restrict__ b1, const int* __restrict__ flag,
    float* __restrict__ h_e)
{
    int f32 = *flag;
    __shared__ float w1s[16 * 32];
    __shared__ float b1s[32];
    int tid = threadIdx.x;
    for (int t = tid; t < 512; t += 256) w1s[t] = ldf(w1, t, f32);
    if (tid < 32) b1s[tid] = ldf(b1, tid, f32);
    __syncthreads();
    int gid = blockIdx.x * 256 + tid;
    int e = gid >> 5, j = gid & 31;
    float acc = b1s[j];
    #pragma unroll
    for (int k = 0; k < 16; k++)
        acc = fmaf(ldf(edge_attr, (size_t)e * 16 + k, f32), w1s[k * 32 + j], acc);
    h_e[gid] = fmaxf(acc, 0.0f);
}

__global__ __launch_bounds__(256) void k_compute_T(
    const void* __restrict__ x, const void* __restrict__ w2,
    const int* __restrict__ flag, void* __restrict__ T, int t32)
{
    int f32 = *flag;
    int n = blockIdx.x, tid = threadIdx.x;
    __shared__ float xs[32];
    if (tid < 32) xs[tid] = ldf(x, (size_t)n * 32 + tid, f32);
    __syncthreads();
    int c0 = tid * 8;
    int j = c0 >> 6, o0 = c0 & 63;
    float acc[8];
    #pragma unroll
    for (int r = 0; r < 8; r++) acc[r] = 0.0f;
    if (f32) {
        const float* wrow = (const float*)w2 + j * 2048 + o0;
        #pragma unroll 4
        for (int i = 0; i < 32; i++) {
            float4 a = *(const float4*)(wrow + i * 64);
            float4 b = *(const float4*)(wrow + i * 64 + 4);
            float xv = xs[i];
            acc[0] = fmaf(xv, a.x, acc[0]); acc[1] = fmaf(xv, a.y, acc[1]);
            acc[2] = fmaf(xv, a.z, acc[2]); acc[3] = fmaf(xv, a.w, acc[3]);
            acc[4] = fmaf(xv, b.x, acc[4]); acc[5] = fmaf(xv, b.y, acc[5]);
            acc[6] = fmaf(xv, b.z, acc[6]); acc[7] = fmaf(xv, b.w, acc[7]);
        }
    } else {
        const uint16_t* wrow = (const uint16_t*)w2 + j * 2048 + o0;
        #pragma unroll 4
        for (int i = 0; i < 32; i++) {
            uint4 wv = *(const uint4*)(wrow + i * 64);
            float xv = xs[i];
            acc[0] = fmaf(xv, blo(wv.x), acc[0]); acc[1] = fmaf(xv, bhi(wv.x), acc[1]);
            acc[2] = fmaf(xv, blo(wv.y), acc[2]); acc[3] = fmaf(xv, bhi(wv.y), acc[3]);
            acc[4] = fmaf(xv, blo(wv.z), acc[4]); acc[5] = fmaf(xv, bhi(wv.z), acc[5]);
            acc[6] = fmaf(xv, blo(wv.w), acc[6]); acc[7] = fmaf(xv, bhi(wv.w), acc[7]);
        }
    }
    size_t base = (size_t)n * 2048 + c0;
    if (t32) {
        float* Tp = (float*)T + base;
        *(float4*)(Tp)     = make_float4(acc[0], acc[1], acc[2], acc[3]);
        *(float4*)(Tp + 4) = make_float4(acc[4], acc[5], acc[6], acc[7]);
    } else {
        uint4 ov;
        ov.x = ((uint32_t)f2bu(acc[1]) << 16) | f2bu(acc[0]);
        ov.y = ((uint32_t)f2bu(acc[3]) << 16) | f2bu(acc[2]);
        ov.z = ((uint32_t)f2bu(acc[5]) << 16) | f2bu(acc[4]);
        ov.w = ((uint32_t)f2bu(acc[7]) << 16) | f2bu(acc[6]);
        *(uint4*)((uint16_t*)T + base) = ov;
    }
}

__global__ __launch_bounds__(256) void k_xb(
    const void* __restrict__ x, const void* __restrict__ b2,
    const int* __restrict__ flag, float* __restrict__ xb)
{
    int f32 = *flag;
    int gid = blockIdx.x * 256 + threadIdx.x;
    int n = gid >> 6, o = gid & 63;
    float acc = 0.0f;
    #pragma unroll
    for (int i = 0; i < 32; i++)
        acc = fmaf(ldf(x, (size_t)n * 32 + i, f32), ldf(b2, i * 64 + o, f32), acc);
    xb[gid] = acc;
}

__global__ __launch_bounds__(256) void k_tcn_t(
    const void* __restrict__ tw1, const void* __restrict__ tw2,
    const void* __restrict__ tw3, const int* __restrict__ flag,
    float* __restrict__ twt)
{
    int f32 = *flag;
    int gid = blockIdx.x * 256 + threadIdx.x;
    if (gid >= 36864) return;
    int t = gid / 12288;
    int rem = gid - t * 12288;
    int k = rem >> 12;
    int rem2 = rem & 4095;
    int i = rem2 >> 6, o = rem2 & 63;
    const void* w = (t == 0) ? tw1 : ((t == 1) ? tw2 : tw3);
    twt[gid] = ldf(w, (size_t)o * 192 + i * 3 + k, f32);
}

__global__ __launch_bounds__(256) void k_edge_msg(
    const float* __restrict__ h_e, const void* __restrict__ T, int t32,
    const float* __restrict__ xb, const int* __restrict__ ei,
    float* __restrict__ agg, float* __restrict__ cnt)
{
    int e = blockIdx.x * 4 + (threadIdx.x >> 6);
    int lane = threadIdx.x & 63;
    if (e >= NE) return;
    int src = ei[e];
    int dst = ei[NE + e];
    const float4* hr = (const float4*)(h_e + (size_t)e * 32);
    float4 h0 = hr[0], h1 = hr[1], h2 = hr[2], h3 = hr[3];
    float4 h4 = hr[4], h5 = hr[5], h6 = hr[6], h7 = hr[7];
    float hv[32] = {h0.x,h0.y,h0.z,h0.w, h1.x,h1.y,h1.z,h1.w,
                    h2.x,h2.y,h2.z,h2.w, h3.x,h3.y,h3.z,h3.w,
                    h4.x,h4.y,h4.z,h4.w, h5.x,h5.y,h5.z,h5.w,
                    h6.x,h6.y,h6.z,h6.w, h7.x,h7.y,h7.z,h7.w};
    size_t base = (size_t)src * 2048 + lane;
    float acc = xb[src * 64 + lane];
    if (t32) {
        const float* Tr = (const float*)T + base;
        #pragma unroll
        for (int j = 0; j < 32; j++) acc = fmaf(hv[j], Tr[j * 64], acc);
    } else {
        const uint16_t* Tr = (const uint16_t*)T + base;
        #pragma unroll
        for (int j = 0; j < 32; j++) acc = fmaf(hv[j], bu2f(Tr[j * 64]), acc);
    }
    unsafeAtomicAdd(&agg[dst * 64 + lane], acc);
    if (lane == 0) unsafeAtomicAdd(&cnt[dst], 1.0f);
}

__global__ __launch_bounds__(256) void k_node_out(
    const float* __restrict__ agg, const float* __restrict__ cnt,
    const void* __restrict__ x, const void* __restrict__ root,
    const void* __restrict__ bias, const void* __restrict__ h_prev,
    const float* __restrict__ twt,
    const void* __restrict__ tb1, const void* __restrict__ tb2,
    const void* __restrict__ tb3,
    const void* __restrict__ proj_w, const void* __restrict__ proj_b,
    const int* __restrict__ flag, void* __restrict__ out)
{
    int f32 = *flag;
    int tid = threadIdx.x;
    int s = tid >> 6, o = tid & 63;
    int n = blockIdx.x * 4 + s;
    const size_t O1 = (size_t)NN * 64;  // element offset of h_hist output
    __shared__ float hg_s[4][64], hp1_s[4][64], hp2_s[4][64], hc_s[4][192];

    float xr = 0.0f;
    #pragma unroll
    for (int i = 0; i < 32; i++)
        xr = fmaf(ldf(x, (size_t)n * 32 + i, f32), ldf(root, i * 64 + o, f32), xr);
    float c = cnt[n];
    float m = agg[n * 64 + o] / fmaxf(c, 1.0f);
    float hg = fmaxf(m + xr + ldf(bias, o, f32), 0.0f);
    float hp1 = ldf(h_prev, (size_t)n * 192 + 64 + o, f32);
    float hp2 = ldf(h_prev, (size_t)n * 192 + 128 + o, f32);
    hg_s[s][o] = hg;
    hp1_s[s][o] = hp1;
    hp2_s[s][o] = hp2;
    stf(out, O1 + (size_t)n * 192 + o, hp1, f32);
    stf(out, O1 + (size_t)n * 192 + 64 + o, hp2, f32);
    stf(out, O1 + (size_t)n * 192 + 128 + o, hg, f32);
    __syncthreads();

    float a1 = ldf(tb1, o, f32), a2 = ldf(tb2, o, f32), a3 = ldf(tb3, o, f32);
    #pragma unroll 4
    for (int i = 0; i < 64; i++) {
        float hgv = hg_s[s][i];
        a1 = fmaf(hp2_s[s][i], twt[i * 64 + o], a1);
        a1 = fmaf(hgv,         twt[4096  + i * 64 + o], a1);
        a2 = fmaf(hp1_s[s][i], twt[12288 + i * 64 + o], a2);
        a2 = fmaf(hgv,         twt[16384 + i * 64 + o], a2);
        a3 = fmaf(hgv,         twt[28672 + i * 64 + o], a3);
    }
    hc_s[s][o] = a1; hc_s[s][64 + o] = a2; hc_s[s][128 + o] = a3;
    __syncthreads();

    float acc = ldf(proj_b, o, f32);
    #pragma unroll 8
    for (int c2 = 0; c2 < 192; c2++)
        acc = fmaf(hc_s[s][c2], ldf(proj_w, (size_t)c2 * 64 + o, f32), acc);
    stf(out, (size_t)n * 64 + o, acc, f32);
}

extern "C" void kernel_launch(void* const* d_in, const int* in_sizes, int n_in,
                              void* d_out, int out_size, void* d_ws, size_t ws_size,
                              hipStream_t stream) {
    const void* x         = d_in[0];
    const void* edge_attr = d_in[1];
    const void* h_prev    = d_in[2];
    const int*  ei        = (const int*)d_in[3];
    const void* w1     = d_in[4];
    const void* b1     = d_in[5];
    const void* w2     = d_in[6];
    const void* b2     = d_in[7];
    const void* root   = d_in[8];
    const void* bias   = d_in[9];
    const void* tw1    = d_in[10];
    const void* tb1    = d_in[11];
    const void* tw2    = d_in[12];
    const void* tb2    = d_in[13];
    const void* tw3    = d_in[14];
    const void* tb3    = d_in[15];
    const void* proj_w = d_in[16];
    const void* proj_b = d_in[17];

    size_t tbytes_f32 = (size_t)NN * 2048 * 4;
    size_t tbytes_b16 = (size_t)NN * 2048 * 2;
    size_t rest = (size_t)NE * 32 * 4 + (size_t)NN * 64 * 4 * 2 + (size_t)NN * 4
                + (size_t)36864 * 4 + 256;
    int t32;
    size_t tbytes;
    if (ws_size >= tbytes_f32 + rest) { t32 = 1; tbytes = tbytes_f32; }
    else { t32 = 0; tbytes = tbytes_b16; }

    char* ws = (char*)d_ws;
    void*  T    = (void*)ws;   ws += tbytes;
    float* h_e  = (float*)ws;  ws += (size_t)NE * 32 * 4;
    float* xb   = (float*)ws;  ws += (size_t)NN * 64 * 4;
    float* agg  = (float*)ws;  ws += (size_t)NN * 64 * 4;
    float* cnt  = (float*)ws;  ws += (size_t)NN * 4;
    float* twt  = (float*)ws;  ws += (size_t)36864 * 4;
    int*   flag = (int*)ws;

    k_detect<<<1, 64, 0, stream>>>(x, flag);
    hipMemsetAsync(agg, 0, (size_t)(NN * 64 + NN) * sizeof(float), stream);
    k_edge_mlp<<<NE * 32 / 256, 256, 0, stream>>>(edge_attr, w1, b1, flag, h_e);
    k_compute_T<<<NN, 256, 0, stream>>>(x, w2, flag, T, t32);
    k_xb<<<NN * 64 / 256, 256, 0, stream>>>(x, b2, flag, xb);
    k_tcn_t<<<144, 256, 0, stream>>>(tw1, tw2, tw3, flag, twt);
    k_edge_msg<<<NE / 4, 256, 0, stream>>>(h_e, T, t32, xb, ei, agg, cnt);
    k_node_out<<<NN / 4, 256, 0, stream>>>(agg, cnt, x, root, bias, h_prev,
                                           twt, tb1, tb2, tb3, proj_w, proj_b,
                                           flag, d_out);
}

// Round 5
// 281.979 us; speedup vs baseline: 1.4442x; 1.4442x over previous
//
#include <hip/hip_runtime.h>
#include <stdint.h>

#define NN 10000
#define NE 100000

__device__ __forceinline__ float bu2f(uint16_t u) {
    return __uint_as_float(((uint32_t)u) << 16);
}
__device__ __forceinline__ float blo(uint32_t v) { return __uint_as_float(v << 16); }
__device__ __forceinline__ float bhi(uint32_t v) { return __uint_as_float(v & 0xffff0000u); }
__device__ __forceinline__ uint16_t f2bu(float f) {  // RNE
    uint32_t u = __float_as_uint(f);
    return (uint16_t)((u + 0x7fffu + ((u >> 16) & 1u)) >> 16);
}
__device__ __forceinline__ float ldf(const void* p, size_t i, int f32) {
    return f32 ? ((const float*)p)[i] : bu2f(((const uint16_t*)p)[i]);
}
__device__ __forceinline__ void stf(void* p, size_t i, float v, int f32) {
    if (f32) ((float*)p)[i] = v;
    else ((uint16_t*)p)[i] = f2bu(v);
}

__global__ void k_detect(const void* __restrict__ x, int* __restrict__ flag) {
    if (threadIdx.x == 0 && blockIdx.x == 0) {
        const uint16_t* p = (const uint16_t*)x;
        int c = 0;
        for (int i = 0; i < 1024; i++) {
            float a = fabsf(bu2f(p[i]));
            if (a > 1e-3f && a < 16.0f) c++;
        }
        *flag = (c < 870) ? 1 : 0;  // 1 = fp32 inputs
    }
}

// ---------- edge MLP: h_e[e,j] = relu(edge_attr[e,:]@w1[:,j]+b1[j]), bf16 out ----------
__global__ __launch_bounds__(256) void k_edge_mlp(
    const void* __restrict__ edge_attr, const void* __restrict__ w1,
    const void* __restrict__ b1, const int* __restrict__ flag,
    uint16_t* __restrict__ h_e)
{
    int f32 = *flag;
    __shared__ float w1s[16 * 32];
    __shared__ float b1s[32];
    int tid = threadIdx.x;
    for (int t = tid; t < 512; t += 256) w1s[t] = ldf(w1, t, f32);
    if (tid < 32) b1s[tid] = ldf(b1, tid, f32);
    __syncthreads();
    int gid = blockIdx.x * 256 + tid;
    int e = gid >> 5, j = gid & 31;
    float acc = b1s[j];
    #pragma unroll
    for (int k = 0; k < 16; k++)
        acc = fmaf(ldf(edge_attr, (size_t)e * 16 + k, f32), w1s[k * 32 + j], acc);
    h_e[gid] = f2bu(fmaxf(acc, 0.0f));
}

// ---------- T[n,j*64+o] bf16 + xb[n,o] fp32; 4 nodes/block ----------
__global__ __launch_bounds__(256) void k_compute_T(
    const void* __restrict__ x, const void* __restrict__ w2,
    const void* __restrict__ b2, const int* __restrict__ flag,
    uint16_t* __restrict__ T, float* __restrict__ xb)
{
    int f32 = *flag;
    int n0 = blockIdx.x * 4;
    int tid = threadIdx.x;
    __shared__ float xs[4][32];
    if (tid < 128) xs[tid >> 5][tid & 31] = ldf(x, (size_t)n0 * 32 + tid, f32);
    __syncthreads();
    int c0 = tid * 8;
    int j = c0 >> 6, o0 = c0 & 63;
    float acc[4][8];
    #pragma unroll
    for (int s = 0; s < 4; s++)
        #pragma unroll
        for (int r = 0; r < 8; r++) acc[s][r] = 0.0f;
    if (f32) {
        const float* wrow = (const float*)w2 + j * 2048 + o0;
        for (int i = 0; i < 32; i++) {
            float4 a = *(const float4*)(wrow + i * 64);
            float4 b = *(const float4*)(wrow + i * 64 + 4);
            #pragma unroll
            for (int s = 0; s < 4; s++) {
                float xv = xs[s][i];
                acc[s][0] = fmaf(xv, a.x, acc[s][0]); acc[s][1] = fmaf(xv, a.y, acc[s][1]);
                acc[s][2] = fmaf(xv, a.z, acc[s][2]); acc[s][3] = fmaf(xv, a.w, acc[s][3]);
                acc[s][4] = fmaf(xv, b.x, acc[s][4]); acc[s][5] = fmaf(xv, b.y, acc[s][5]);
                acc[s][6] = fmaf(xv, b.z, acc[s][6]); acc[s][7] = fmaf(xv, b.w, acc[s][7]);
            }
        }
    } else {
        const uint16_t* wrow = (const uint16_t*)w2 + j * 2048 + o0;
        for (int i = 0; i < 32; i++) {
            uint4 wv = *(const uint4*)(wrow + i * 64);
            float w0 = blo(wv.x), w1_ = bhi(wv.x), w2_ = blo(wv.y), w3 = bhi(wv.y);
            float w4 = blo(wv.z), w5 = bhi(wv.z), w6 = blo(wv.w), w7 = bhi(wv.w);
            #pragma unroll
            for (int s = 0; s < 4; s++) {
                float xv = xs[s][i];
                acc[s][0] = fmaf(xv, w0, acc[s][0]); acc[s][1] = fmaf(xv, w1_, acc[s][1]);
                acc[s][2] = fmaf(xv, w2_, acc[s][2]); acc[s][3] = fmaf(xv, w3, acc[s][3]);
                acc[s][4] = fmaf(xv, w4, acc[s][4]); acc[s][5] = fmaf(xv, w5, acc[s][5]);
                acc[s][6] = fmaf(xv, w6, acc[s][6]); acc[s][7] = fmaf(xv, w7, acc[s][7]);
            }
        }
    }
    #pragma unroll
    for (int s = 0; s < 4; s++) {
        uint4 ov;
        ov.x = ((uint32_t)f2bu(acc[s][1]) << 16) | f2bu(acc[s][0]);
        ov.y = ((uint32_t)f2bu(acc[s][3]) << 16) | f2bu(acc[s][2]);
        ov.z = ((uint32_t)f2bu(acc[s][5]) << 16) | f2bu(acc[s][4]);
        ov.w = ((uint32_t)f2bu(acc[s][7]) << 16) | f2bu(acc[s][6]);
        *(uint4*)(T + (size_t)(n0 + s) * 2048 + c0) = ov;
    }
    // fused xb: one (node, channel) per thread
    int s = tid >> 6, o = tid & 63;
    float a = 0.0f;
    #pragma unroll
    for (int i = 0; i < 32; i++)
        a = fmaf(xs[s][i], ldf(b2, i * 64 + o, f32), a);
    xb[(size_t)(n0 + s) * 64 + o] = a;
}

// ---------- transpose tcn weights [o,i,k] -> twt[t][k][i][o], fp32 ----------
__global__ __launch_bounds__(256) void k_tcn_t(
    const void* __restrict__ tw1, const void* __restrict__ tw2,
    const void* __restrict__ tw3, const int* __restrict__ flag,
    float* __restrict__ twt)
{
    int f32 = *flag;
    int gid = blockIdx.x * 256 + threadIdx.x;
    if (gid >= 36864) return;
    int t = gid / 12288;
    int rem = gid - t * 12288;
    int k = rem >> 12;
    int rem2 = rem & 4095;
    int i = rem2 >> 6, o = rem2 & 63;
    const void* w = (t == 0) ? tw1 : ((t == 1) ? tw2 : tw3);
    twt[gid] = ldf(w, (size_t)o * 192 + i * 3 + k, f32);
}

// ---------- per-edge messages (R2 structure; bf16 h_e) ----------
__global__ __launch_bounds__(256) void k_edge_msg(
    const uint16_t* __restrict__ h_e, const uint16_t* __restrict__ T,
    const float* __restrict__ xb, const int* __restrict__ ei,
    float* __restrict__ agg, float* __restrict__ cnt)
{
    int e = blockIdx.x * 4 + (threadIdx.x >> 6);
    int lane = threadIdx.x & 63;
    if (e >= NE) return;
    int src = ei[e];
    int dst = ei[NE + e];
    const uint4* hp = (const uint4*)(h_e + (size_t)e * 32);  // 64B, aligned
    uint4 a = hp[0], b = hp[1], c = hp[2], d = hp[3];
    float hv[32] = {blo(a.x), bhi(a.x), blo(a.y), bhi(a.y),
                    blo(a.z), bhi(a.z), blo(a.w), bhi(a.w),
                    blo(b.x), bhi(b.x), blo(b.y), bhi(b.y),
                    blo(b.z), bhi(b.z), blo(b.w), bhi(b.w),
                    blo(c.x), bhi(c.x), blo(c.y), bhi(c.y),
                    blo(c.z), bhi(c.z), blo(c.w), bhi(c.w),
                    blo(d.x), bhi(d.x), blo(d.y), bhi(d.y),
                    blo(d.z), bhi(d.z), blo(d.w), bhi(d.w)};
    size_t base = (size_t)src * 2048 + lane;
    float acc = xb[(size_t)src * 64 + lane];
    const uint16_t* Tr = T + base;
    #pragma unroll
    for (int j = 0; j < 32; j++) acc = fmaf(hv[j], bu2f(Tr[j * 64]), acc);
    unsafeAtomicAdd(&agg[(size_t)dst * 64 + lane], acc);
    if (lane == 0) unsafeAtomicAdd(&cnt[dst], 1.0f);
}

// ---------- per-node finalize (R2 verbatim) ----------
__global__ __launch_bounds__(256) void k_node_out(
    const float* __restrict__ agg, const float* __restrict__ cnt,
    const void* __restrict__ x, const void* __restrict__ root,
    const void* __restrict__ bias, const void* __restrict__ h_prev,
    const float* __restrict__ twt,
    const void* __restrict__ tb1, const void* __restrict__ tb2,
    const void* __restrict__ tb3,
    const void* __restrict__ proj_w, const void* __restrict__ proj_b,
    const int* __restrict__ flag, void* __restrict__ out)
{
    int f32 = *flag;
    int tid = threadIdx.x;
    int s = tid >> 6, o = tid & 63;
    int n = blockIdx.x * 4 + s;
    const size_t O1 = (size_t)NN * 64;  // element offset of h_hist output
    __shared__ float hg_s[4][64], hp1_s[4][64], hp2_s[4][64], hc_s[4][192];

    float xr = 0.0f;
    #pragma unroll
    for (int i = 0; i < 32; i++)
        xr = fmaf(ldf(x, (size_t)n * 32 + i, f32), ldf(root, i * 64 + o, f32), xr);
    float c = cnt[n];
    float m = agg[(size_t)n * 64 + o] / fmaxf(c, 1.0f);
    float hg = fmaxf(m + xr + ldf(bias, o, f32), 0.0f);
    float hp1 = ldf(h_prev, (size_t)n * 192 + 64 + o, f32);
    float hp2 = ldf(h_prev, (size_t)n * 192 + 128 + o, f32);
    hg_s[s][o] = hg;
    hp1_s[s][o] = hp1;
    hp2_s[s][o] = hp2;
    stf(out, O1 + (size_t)n * 192 + o, hp1, f32);
    stf(out, O1 + (size_t)n * 192 + 64 + o, hp2, f32);
    stf(out, O1 + (size_t)n * 192 + 128 + o, hg, f32);
    __syncthreads();

    // TCN closed form: b1 = hp2@w1[k0]+hg@w1[k1]; b2 = hp1@w2[k0]+hg@w2[k1]; b3 = hg@w3[k1]
    float a1 = ldf(tb1, o, f32), a2 = ldf(tb2, o, f32), a3 = ldf(tb3, o, f32);
    #pragma unroll 4
    for (int i = 0; i < 64; i++) {
        float hgv = hg_s[s][i];
        a1 = fmaf(hp2_s[s][i], twt[i * 64 + o], a1);
        a1 = fmaf(hgv,         twt[4096  + i * 64 + o], a1);
        a2 = fmaf(hp1_s[s][i], twt[12288 + i * 64 + o], a2);
        a2 = fmaf(hgv,         twt[16384 + i * 64 + o], a2);
        a3 = fmaf(hgv,         twt[28672 + i * 64 + o], a3);
    }
    hc_s[s][o] = a1; hc_s[s][64 + o] = a2; hc_s[s][128 + o] = a3;
    __syncthreads();

    float acc = ldf(proj_b, o, f32);
    #pragma unroll 8
    for (int c2 = 0; c2 < 192; c2++)
        acc = fmaf(hc_s[s][c2], ldf(proj_w, (size_t)c2 * 64 + o, f32), acc);
    stf(out, (size_t)n * 64 + o, acc, f32);
}

extern "C" void kernel_launch(void* const* d_in, const int* in_sizes, int n_in,
                              void* d_out, int out_size, void* d_ws, size_t ws_size,
                              hipStream_t stream) {
    const void* x         = d_in[0];
    const void* edge_attr = d_in[1];
    const void* h_prev    = d_in[2];
    const int*  ei        = (const int*)d_in[3];
    const void* w1     = d_in[4];
    const void* b1     = d_in[5];
    const void* w2     = d_in[6];
    const void* b2     = d_in[7];
    const void* root   = d_in[8];
    const void* bias   = d_in[9];
    const void* tw1    = d_in[10];
    const void* tb1    = d_in[11];
    const void* tw2    = d_in[12];
    const void* tb2    = d_in[13];
    const void* tw3    = d_in[14];
    const void* tb3    = d_in[15];
    const void* proj_w = d_in[16];
    const void* proj_b = d_in[17];

    char* ws = (char*)d_ws;
    uint16_t* T   = (uint16_t*)ws; ws += (size_t)NN * 2048 * 2;  // 40.96 MB
    uint16_t* h_e = (uint16_t*)ws; ws += (size_t)NE * 32 * 2;    // 6.4 MB
    float* xb     = (float*)ws;    ws += (size_t)NN * 64 * 4;    // 2.56 MB
    float* agg    = (float*)ws;    ws += (size_t)NN * 64 * 4;    // 2.56 MB (contig w/ cnt)
    float* cnt    = (float*)ws;    ws += (size_t)NN * 4;         // 40 KB
    float* twt    = (float*)ws;    ws += (size_t)36864 * 4;      // 147 KB
    int*   flag   = (int*)ws;

    k_detect<<<1, 64, 0, stream>>>(x, flag);
    hipMemsetAsync(agg, 0, (size_t)(NN * 64 + NN) * sizeof(float), stream);
    k_edge_mlp<<<NE * 32 / 256, 256, 0, stream>>>(edge_attr, w1, b1, flag, h_e);
    k_compute_T<<<NN / 4, 256, 0, stream>>>(x, w2, b2, flag, T, xb);
    k_tcn_t<<<144, 256, 0, stream>>>(tw1, tw2, tw3, flag, twt);
    k_edge_msg<<<NE / 4, 256, 0, stream>>>(h_e, T, xb, ei, agg, cnt);
    k_node_out<<<NN / 4, 256, 0, stream>>>(agg, cnt, x, root, bias, h_prev,
                                           twt, tb1, tb2, tb3, proj_w, proj_b,
                                           flag, d_out);
}